// Round 12
// baseline (396.002 us; speedup 1.0000x reference)
//
#include <hip/hip_runtime.h>
#include <hip/hip_bf16.h>

typedef __bf16 bf16x8 __attribute__((ext_vector_type(8)));
typedef float f32x4 __attribute__((ext_vector_type(4)));
typedef float f32x16 __attribute__((ext_vector_type(16)));

#define MFMA_B16(a, b, c) __builtin_amdgcn_mfma_f32_16x16x32_bf16((a), (b), (c), 0, 0, 0)
#define MFMA32_B16(a, b, c) __builtin_amdgcn_mfma_f32_32x32x16_bf16((a), (b), (c), 0, 0, 0)
#define GLD16(g, l)                                                              \
    __builtin_amdgcn_global_load_lds((__attribute__((address_space(1))) void*)(g), \
                                     (__attribute__((address_space(3))) void*)(l), \
                                     16, 0, 0)

__device__ __forceinline__ float bfu2f(unsigned short u) {
    return __uint_as_float(((unsigned)u) << 16);
}
__device__ __forceinline__ unsigned short f2bfu(float f) {
    unsigned u = __float_as_uint(f);
    u += 0x7fffu + ((u >> 16) & 1u);   // RNE (finite values)
    return (unsigned short)(u >> 16);
}
__device__ __forceinline__ float fexp2(float x) {
#if __has_builtin(__builtin_amdgcn_exp2f)
    return __builtin_amdgcn_exp2f(x);
#else
    return __expf(x * 0.69314718f);
#endif
}
__device__ __forceinline__ unsigned cvtpk_bf16(float lo_, float hi_) {
    unsigned r;
    asm("v_cvt_pk_bf16_f32 %0, %1, %2" : "=v"(r) : "v"(lo_), "v"(hi_));
    return r;
}
// HW semantics of v_permlane32_swap_b32 (vdst=a, vsrc=b): a's HIGH half swaps
// with b's LOW half. Result: a_new = {a_lo, b_lo}; b_new = {a_hi, b_hi}.
__device__ __forceinline__ void plswap(unsigned& a, unsigned& b) {
#if __has_builtin(__builtin_amdgcn_permlane32_swap)
    typedef int v2i __attribute__((ext_vector_type(2)));
    v2i r = __builtin_amdgcn_permlane32_swap((int)a, (int)b, false, false);
    a = (unsigned)r.x;
    b = (unsigned)r.y;
#else
    unsigned pa_ = (unsigned)__shfl_xor((int)a, 32);
    unsigned pb_ = (unsigned)__shfl_xor((int)b, 32);
    bool hi = (threadIdx.x & 63) >= 32;
    unsigned na = hi ? pb_ : a;
    unsigned nb = hi ? b : pa_;
    a = na;
    b = nb;
#endif
}

// ---------------- fused weight f32 -> bf16 convert ----------------
__global__ __launch_bounds__(256) void cvt5_f32_bf16(const float* __restrict__ s0,
                                                     const float* __restrict__ s1,
                                                     const float* __restrict__ s2,
                                                     const float* __restrict__ s3,
                                                     const float* __restrict__ s4,
                                                     unsigned short* __restrict__ dst) {
    int wsel = blockIdx.x >> 10;
    int i = (blockIdx.x & 1023) * 256 + threadIdx.x;
    const float* src = s0;
    if (wsel == 1) src = s1;
    else if (wsel == 2) src = s2;
    else if (wsel == 3) src = s3;
    else if (wsel == 4) src = s4;
    float4 v = ((const float4*)src)[i];
    ((ushort4*)dst)[wsel * 262144 + i] =
        make_ushort4(f2bfu(v.x), f2bfu(v.y), f2bfu(v.z), f2bfu(v.w));
}

// ---------------- LN1: f32 in -> bf16 out ----------------
__global__ __launch_bounds__(256) void ln1_kernel(const float* __restrict__ in1,
                                                  const float* __restrict__ gam,
                                                  const float* __restrict__ bet,
                                                  unsigned short* __restrict__ outb) {
    int row = blockIdx.x, tid = threadIdx.x;
    size_t base = (size_t)row * 1024 + tid * 4;
    float4 v = *(const float4*)(in1 + base);
    float s = v.x + v.y + v.z + v.w;
    float sq = v.x * v.x + v.y * v.y + v.z * v.z + v.w * v.w;
#pragma unroll
    for (int m = 1; m < 64; m <<= 1) {
        s += __shfl_xor(s, m);
        sq += __shfl_xor(sq, m);
    }
    __shared__ float red[8];
    int w = tid >> 6;
    if ((tid & 63) == 0) { red[w] = s; red[w + 4] = sq; }
    __syncthreads();
    s = red[0] + red[1] + red[2] + red[3];
    sq = red[4] + red[5] + red[6] + red[7];
    float mean = s * (1.0f / 1024.0f);
    float var = fmaxf(sq * (1.0f / 1024.0f) - mean * mean, 0.0f);
    float rstd = rsqrtf(var + 1e-5f);
    float4 g4 = *(const float4*)(gam + tid * 4);
    float4 b4 = *(const float4*)(bet + tid * 4);
    *(ushort4*)(outb + base) = make_ushort4(
        f2bfu((v.x - mean) * rstd * g4.x + b4.x), f2bfu((v.y - mean) * rstd * g4.y + b4.y),
        f2bfu((v.z - mean) * rstd * g4.z + b4.z), f2bfu((v.w - mean) * rstd * g4.w + b4.w));
}

// ---------------- LN2: bf16 xn + bf16 att -> bf16 out ----------------
__global__ __launch_bounds__(256) void ln2_kernel(const unsigned short* __restrict__ in1,
                                                  const unsigned short* __restrict__ in2,
                                                  const float* __restrict__ gam,
                                                  const float* __restrict__ bet,
                                                  unsigned short* __restrict__ outb) {
    int row = blockIdx.x, tid = threadIdx.x;
    size_t base = (size_t)row * 1024 + tid * 4;
    ushort4 a = *(const ushort4*)(in1 + base);
    ushort4 c = *(const ushort4*)(in2 + base);
    float4 v = make_float4(bfu2f(a.x) + bfu2f(c.x), bfu2f(a.y) + bfu2f(c.y),
                           bfu2f(a.z) + bfu2f(c.z), bfu2f(a.w) + bfu2f(c.w));
    float s = v.x + v.y + v.z + v.w;
    float sq = v.x * v.x + v.y * v.y + v.z * v.z + v.w * v.w;
#pragma unroll
    for (int m = 1; m < 64; m <<= 1) {
        s += __shfl_xor(s, m);
        sq += __shfl_xor(sq, m);
    }
    __shared__ float red[8];
    int w = tid >> 6;
    if ((tid & 63) == 0) { red[w] = s; red[w + 4] = sq; }
    __syncthreads();
    s = red[0] + red[1] + red[2] + red[3];
    sq = red[4] + red[5] + red[6] + red[7];
    float mean = s * (1.0f / 1024.0f);
    float var = fmaxf(sq * (1.0f / 1024.0f) - mean * mean, 0.0f);
    float rstd = rsqrtf(var + 1e-5f);
    float4 g4 = *(const float4*)(gam + tid * 4);
    float4 b4 = *(const float4*)(bet + tid * 4);
    *(ushort4*)(outb + base) = make_ushort4(
        f2bfu((v.x - mean) * rstd * g4.x + b4.x), f2bfu((v.y - mean) * rstd * g4.y + b4.y),
        f2bfu((v.z - mean) * rstd * g4.z + b4.z), f2bfu((v.w - mean) * rstd * g4.w + b4.w));
}

// ---------------- BT-GEMM, 8-phase 256x256 schedule (m201 structure) ----------------
// MODE 0: QKV fused (N=3072): col<1024 -> q*0.125log2e, <2048 -> k, else vT[b,h,d,s]
// MODE 1: bias+relu -> bf16. MODE 2: bias + bf16 resid -> f32.
template <int MODE>
__global__ __launch_bounds__(512, 2) void gemm8(const unsigned short* __restrict__ A,
                                                const unsigned short* __restrict__ Bw,
                                                const float* __restrict__ bias,
                                                const unsigned short* __restrict__ resid,
                                                void* __restrict__ O0, void* __restrict__ O1,
                                                void* __restrict__ O2, int M, int N, int K) {
    __shared__ unsigned short As[4][8192];   // [buf*2+half][128*64]
    __shared__ unsigned short Bs[4][8192];
    int nt = N >> 8;
    int bid = blockIdx.x;
    int nwg = gridDim.x;                     // divisible by 8
    int swz = (bid & 7) * (nwg >> 3) + (bid >> 3);
    int mt = swz / nt, ntl = swz % nt;
    int mbase = mt << 8, nbase = ntl << 8;
    int tid = threadIdx.x;
    int w = tid >> 6, l = tid & 63;
    int wm = w >> 2, wn = w & 3;
    int lr = l & 15, lg = l >> 4;
    int lx = lr & 7;
    int brow = (wn & 1) * 64;

    int srow = tid >> 3;
    int csrc = (tid & 7) ^ (srow & 7);
    const unsigned short* aRow = A + (size_t)(mbase + srow) * K + csrc * 8;
    const unsigned short* bRow = Bw + (size_t)(nbase + srow) * K + csrc * 8;

    const int NT = K >> 6;                   // 16
    auto stA = [&](int buf, int h, int t) {
        if (t >= NT) return;
        const unsigned short* s0 = aRow + (size_t)(h * 128) * K + t * 64;
        GLD16(s0, &As[buf * 2 + h][w * 512]);
        GLD16(s0 + (size_t)64 * K, &As[buf * 2 + h][4096 + w * 512]);
    };
    auto stB = [&](int buf, int h, int t) {
        if (t >= NT) return;
        const unsigned short* s0 = bRow + (size_t)(h * 128) * K + t * 64;
        GLD16(s0, &Bs[buf * 2 + h][w * 512]);
        GLD16(s0 + (size_t)64 * K, &Bs[buf * 2 + h][4096 + w * 512]);
    };

    f32x4 acc[8][4] = {};
    bf16x8 afr[4][2], bq0[2][2], bq1[2][2];

    auto rdA = [&](int buf, int mq) {
        const unsigned short* base = &As[buf * 2 + wm][0];
#pragma unroll
        for (int mf = 0; mf < 4; mf++)
#pragma unroll
            for (int ks = 0; ks < 2; ks++)
                afr[mf][ks] = *(const bf16x8*)(base + (mq * 64 + mf * 16 + lr) * 64 +
                                               (((ks * 4 + lg) ^ lx) << 3));
    };
    auto rdB = [&](int buf, int nq, bf16x8 (&bf)[2][2]) {
        const unsigned short* base = &Bs[buf * 2 + (wn >> 1)][0];
#pragma unroll
        for (int nf = 0; nf < 2; nf++)
#pragma unroll
            for (int ks = 0; ks < 2; ks++)
                bf[nf][ks] = *(const bf16x8*)(base + (brow + nq * 32 + nf * 16 + lr) * 64 +
                                              (((ks * 4 + lg) ^ lx) << 3));
    };
    auto MM = [&](int mq, int nq, bf16x8 (&bf)[2][2]) {
        __builtin_amdgcn_s_setprio(1);
#pragma unroll
        for (int mf = 0; mf < 4; mf++)
#pragma unroll
            for (int nf = 0; nf < 2; nf++)
#pragma unroll
                for (int ks = 0; ks < 2; ks++)
                    acc[mq * 4 + mf][nq * 2 + nf] =
                        MFMA_B16(afr[mf][ks], bf[nf][ks], acc[mq * 4 + mf][nq * 2 + nf]);
        __builtin_amdgcn_s_setprio(0);
    };
#define BARX __builtin_amdgcn_s_barrier()
#define LGK0 do { asm volatile("s_waitcnt lgkmcnt(0)" ::: "memory"); \
                  __builtin_amdgcn_sched_barrier(0); } while (0)
#define VMC(n) asm volatile("s_waitcnt vmcnt(" #n ")" ::: "memory")

    stA(0, 0, 0); stA(0, 1, 0); stB(0, 0, 0); stB(0, 1, 0); stB(1, 0, 1); stB(1, 1, 1);
    VMC(4);
    BARX;

    int NIT = NT >> 1;
    for (int i = 0; i < NIT; i++) {
        int t0 = 2 * i, t1 = t0 + 1;
        bool lastI = (i == NIT - 1);
        rdA(0, 0); rdB(0, 0, bq0); stA(1, 0, t1);
        BARX; LGK0; MM(0, 0, bq0); BARX;
        rdB(0, 1, bq1); stA(1, 1, t1);
        BARX; LGK0; MM(0, 1, bq1); BARX;
        rdA(0, 1); stB(0, 0, t0 + 2);
        BARX; LGK0; MM(1, 1, bq1); BARX;
        stB(0, 1, t0 + 2);
        if (lastI) { VMC(0); } else { VMC(4); }
        BARX; MM(1, 0, bq0); BARX;
        rdA(1, 0); rdB(1, 0, bq0); stA(0, 0, t0 + 2);
        BARX; LGK0; MM(0, 0, bq0); BARX;
        rdB(1, 1, bq1); stA(0, 1, t0 + 2);
        BARX; LGK0; MM(0, 1, bq1); BARX;
        rdA(1, 1); stB(1, 0, t1 + 2);
        BARX; LGK0; MM(1, 1, bq1); BARX;
        stB(1, 1, t1 + 2);
        if (!lastI) { VMC(4); }
        BARX; MM(1, 0, bq0); BARX;
    }

#pragma unroll
    for (int m = 0; m < 8; m++) {
        int row = mbase + wm * 128 + (m >> 2) * 64 + (m & 3) * 16 + lg * 4;
#pragma unroll
        for (int n = 0; n < 4; n++) {
            int col = nbase + wn * 64 + (n >> 1) * 32 + (n & 1) * 16 + lr;
            if constexpr (MODE == 0) {
                int wsel = col >> 10;
                int cl = col & 1023;
                if (wsel == 2) {
                    int hh = cl >> 6, dd = cl & 63;
                    int bb = row >> 11, ss = row & 2047;
                    unsigned short t4[4];
#pragma unroll
                    for (int j = 0; j < 4; j++) t4[j] = f2bfu(acc[m][n][j]);
                    size_t vtidx = ((size_t)((bb * 16 + hh) * 64 + dd)) * 2048 + ss;
                    *(uint2*)((unsigned short*)O2 + vtidx) = *(uint2*)t4;
                } else {
                    unsigned short* out = (wsel == 0) ? (unsigned short*)O0 : (unsigned short*)O1;
                    float sc = (wsel == 0) ? 0.18033688f : 1.0f;   // 0.125*log2e folded into Q
#pragma unroll
                    for (int j = 0; j < 4; j++)
                        out[(size_t)(row + j) * 1024 + cl] = f2bfu(acc[m][n][j] * sc);
                }
            } else {
                float bv = bias[col];
#pragma unroll
                for (int j = 0; j < 4; j++) {
                    float v = acc[m][n][j] + bv;
                    size_t idx = (size_t)(row + j) * N + col;
                    if constexpr (MODE == 1) {
                        ((unsigned short*)O0)[idx] = f2bfu(fmaxf(v, 0.0f));
                    } else {
                        ((float*)O0)[idx] = v + bfu2f(resid[idx]);
                    }
                }
            }
        }
    }
#undef BARX
#undef LGK0
#undef VMC
}

// ---------------- flash attention: 4-buffer, unrolled x4, XOR-folded addresses ----------------
// 8 waves x QBLK=32, KVBLK=64, zero-shift softmax, swapped-QK 32x32 MFMA.
// All LDS read addrs = abase ^ (kc<<5) + compile-time immediates (buffer j*8192,
// row-half 4096). Per step: vmcnt(2) -> s_barrier -> stage(s+2) -> compute(s);
// stage target buf[(s+2)&3] last read 2 barriers ago.
__global__ __launch_bounds__(512) void attn_kernel(const unsigned short* __restrict__ qq,
                                                   const unsigned short* __restrict__ kk,
                                                   const unsigned short* __restrict__ vT,
                                                   unsigned short* __restrict__ attb) {
    __shared__ unsigned short Ks[4][4096];   // [buf][key][d], 8 KiB/buf, chunk-XOR swizzled
    __shared__ unsigned short Vs[4][4096];   // [buf][d][key]

    int bid = blockIdx.x;
    int swz = (bid & 7) * (gridDim.x >> 3) + (bid >> 3);   // gridDim=1024, %8==0
    int qi = swz & 7, h = (swz >> 3) & 15, b = swz >> 7;
    int tid = threadIdx.x, w = tid >> 6, l = tid & 63;
    int lo = l & 31, hi = l >> 5;
    int q0 = qi * 256 + w * 32;

    const unsigned short* qp = qq + ((size_t)((b * 2048 + q0 + lo) * 16 + h)) * 64 + hi * 8;
    bf16x8 qf[4];
#pragma unroll
    for (int kc = 0; kc < 4; kc++) qf[kc] = *(const bf16x8*)(qp + kc * 16);

    int srow = w * 8 + (l >> 3);
    int schunk = (l & 7) ^ ((l >> 3) & 7);
    const unsigned short* kptr = kk + ((size_t)((b * 2048 + srow) * 16 + h)) * 64 + schunk * 8;
    const unsigned short* vptr = vT + ((size_t)((b * 16 + h) * 64 + srow)) * 2048 + schunk * 8;

    // one lane-constant byte offset generates ALL 16 tile-read addresses:
    // K(tt,kc): Ks + j*8192 + tt*4096 + (abase ^ (kc<<5))
    // V(hf,ks): Vs + j*8192 + hf*4096 + (abase ^ (ks<<5))
    int abase = lo * 128 + ((hi ^ (lo & 7)) << 4);
    const char* ldsK = (const char*)&Ks[0][0];
    const char* ldsV = (const char*)&Vs[0][0];

    f32x16 od0 = {}, od1 = {};
    float ssum = 0.f;

    GLD16(kptr, &Ks[0][w * 512]); GLD16(vptr, &Vs[0][w * 512]);
    kptr += 65536; vptr += 64;
    GLD16(kptr, &Ks[1][w * 512]); GLD16(vptr, &Vs[1][w * 512]);
    kptr += 65536; vptr += 64;

    for (int i = 0; i < 8; i++) {
#pragma unroll
        for (int j = 0; j < 4; j++) {
            if (j < 3) { asm volatile("s_waitcnt vmcnt(2)" ::: "memory"); }
            else if (i < 7) { asm volatile("s_waitcnt vmcnt(2)" ::: "memory"); }
            else { asm volatile("s_waitcnt vmcnt(0)" ::: "memory"); }
            __builtin_amdgcn_s_barrier();            // tile s complete block-wide
            __builtin_amdgcn_sched_barrier(0);       // keep reads below the barrier
            if (i * 4 + j + 2 < 32) {                // stage tile s+2 into buf (j+2)&3
                GLD16(kptr, &Ks[(j + 2) & 3][w * 512]);
                GLD16(vptr, &Vs[(j + 2) & 3][w * 512]);
                kptr += 65536; vptr += 64;
            }
            // ---- QK^T (swapped): St[key][q] ----
            f32x16 sacc[2];
            __builtin_amdgcn_s_setprio(1);
#pragma unroll
            for (int tt = 0; tt < 2; tt++) {
                f32x16 sv = {};
#pragma unroll
                for (int kc = 0; kc < 4; kc++) {
                    bf16x8 a = *(const bf16x8*)(ldsK + j * 8192 + tt * 4096 +
                                                (abase ^ (kc << 5)));
                    sv = MFMA32_B16(a, qf[kc], sv);
                }
                sacc[tt] = sv;
            }
            __builtin_amdgcn_s_setprio(0);
            // ---- zero-shift softmax (ssum lane-local; combined in epilogue) ----
            float p[32];
            float ps0 = 0.f, ps1 = 0.f;
#pragma unroll
            for (int r = 0; r < 16; r++) {
                float e0 = fexp2(sacc[0][r]);
                float e1 = fexp2(sacc[1][r]);
                p[r] = e0;
                p[16 + r] = e1;
                ps0 += e0;
                ps1 += e1;
            }
            ssum += ps0 + ps1;
            // ---- P -> bf16 A-frags in-register + PV ----
#pragma unroll
            for (int tt = 0; tt < 2; tt++) {
                unsigned wv[8];
#pragma unroll
                for (int ii = 0; ii < 8; ii++)
                    wv[ii] = cvtpk_bf16(p[tt * 16 + 2 * ii], p[tt * 16 + 2 * ii + 1]);
                plswap(wv[0], wv[2]);
                plswap(wv[1], wv[3]);
                plswap(wv[4], wv[6]);
                plswap(wv[5], wv[7]);
                union { unsigned u[4]; bf16x8 v; } c0, c1;
                c0.u[0] = wv[0]; c0.u[1] = wv[1]; c0.u[2] = wv[2]; c0.u[3] = wv[3];
                c1.u[0] = wv[4]; c1.u[1] = wv[5]; c1.u[2] = wv[6]; c1.u[3] = wv[7];
                __builtin_amdgcn_s_setprio(1);
#pragma unroll
                for (int sub = 0; sub < 2; sub++) {
                    int ks = tt * 2 + sub;
                    bf16x8 pa = sub ? c1.v : c0.v;
                    bf16x8 v0 = *(const bf16x8*)(ldsV + j * 8192 + (abase ^ (ks << 5)));
                    bf16x8 v1 = *(const bf16x8*)(ldsV + j * 8192 + 4096 + (abase ^ (ks << 5)));
                    od0 = MFMA32_B16(pa, v0, od0);
                    od1 = MFMA32_B16(pa, v1, od1);
                }
                __builtin_amdgcn_s_setprio(0);
            }
        }
    }

    ssum += __shfl_xor(ssum, 32);                // deferred cross-lane row-sum combine
#pragma unroll
    for (int r = 0; r < 16; r++) {
        int crow = (r & 3) + ((r >> 2) << 3) + (hi << 2);
        float rs = 1.0f / __shfl(ssum, crow);
        int q = q0 + crow;
        size_t base = ((size_t)((b * 2048 + q) * 16 + h)) * 64;
        attb[base + lo] = f2bfu(od0[r] * rs);
        attb[base + 32 + lo] = f2bfu(od1[r] * rs);
    }
}

// ---------------- launch ----------------
extern "C" void kernel_launch(void* const* d_in, const int* in_sizes, int n_in,
                              void* d_out, int out_size, void* d_ws, size_t ws_size,
                              hipStream_t stream) {
    const float* x = (const float*)d_in[0];
    const float* wq = (const float*)d_in[1];
    const float* wk = (const float*)d_in[2];
    const float* wv = (const float*)d_in[3];
    const float* ln1_g = (const float*)d_in[4];
    const float* ln1_b = (const float*)d_in[5];
    const float* ln2_g = (const float*)d_in[6];
    const float* ln2_b = (const float*)d_in[7];
    const float* w1 = (const float*)d_in[8];
    const float* b1 = (const float*)d_in[9];
    const float* w2 = (const float*)d_in[10];
    const float* b2 = (const float*)d_in[11];

    const size_t NB = 33554432;                 // bytes per bf16 [B,S,D] buffer
    char* ws = (char*)d_ws;
    unsigned short* xn_b = (unsigned short*)(ws);
    unsigned short* q_b = (unsigned short*)(ws + NB);
    unsigned short* k_b = (unsigned short*)(ws + 2 * NB);
    unsigned short* vT_b = (unsigned short*)(ws + 3 * NB);
    unsigned short* att_b = (unsigned short*)(ws + 4 * NB);
    unsigned short* wq_b = (unsigned short*)(ws + 5 * NB);   // wq,wk,wv,w1,w2 contiguous
    unsigned short* w1_b = wq_b + 3145728;
    unsigned short* w2_b = w1_b + 1048576;
    // stream-ordered reuse:
    unsigned short* xt_b = q_b;                 // q dead after attention
    unsigned short* h_b = k_b;                  // k dead after attention

    dim3 blk(256);
    cvt5_f32_bf16<<<5120, blk, 0, stream>>>(wq, wk, wv, w1, w2, wq_b);
    ln1_kernel<<<16384, blk, 0, stream>>>(x, ln1_g, ln1_b, xn_b);

    gemm8<0><<<768, dim3(512), 0, stream>>>(xn_b, wq_b, nullptr, nullptr,
                                            q_b, k_b, vT_b, 16384, 3072, 1024);

    attn_kernel<<<1024, dim3(512), 0, stream>>>(q_b, k_b, vT_b, att_b);

    ln2_kernel<<<16384, blk, 0, stream>>>(xn_b, att_b, ln2_g, ln2_b, xt_b);

    gemm8<1><<<256, dim3(512), 0, stream>>>(xt_b, w1_b, b1, nullptr,
                                            h_b, nullptr, nullptr, 16384, 1024, 1024);
    gemm8<2><<<256, dim3(512), 0, stream>>>(h_b, w2_b, b2, xt_b,
                                            d_out, nullptr, nullptr, 16384, 1024, 1024);
}

// Round 13
// 374.580 us; speedup vs baseline: 1.0572x; 1.0572x over previous
//
#include <hip/hip_runtime.h>
#include <hip/hip_bf16.h>

typedef __bf16 bf16x8 __attribute__((ext_vector_type(8)));
typedef float f32x4 __attribute__((ext_vector_type(4)));
typedef float f32x16 __attribute__((ext_vector_type(16)));

#define MFMA_B16(a, b, c) __builtin_amdgcn_mfma_f32_16x16x32_bf16((a), (b), (c), 0, 0, 0)
#define MFMA32_B16(a, b, c) __builtin_amdgcn_mfma_f32_32x32x16_bf16((a), (b), (c), 0, 0, 0)
#define GLD16(g, l)                                                              \
    __builtin_amdgcn_global_load_lds((__attribute__((address_space(1))) void*)(g), \
                                     (__attribute__((address_space(3))) void*)(l), \
                                     16, 0, 0)

__device__ __forceinline__ float bfu2f(unsigned short u) {
    return __uint_as_float(((unsigned)u) << 16);
}
__device__ __forceinline__ unsigned short f2bfu(float f) {
    unsigned u = __float_as_uint(f);
    u += 0x7fffu + ((u >> 16) & 1u);   // RNE (finite values)
    return (unsigned short)(u >> 16);
}
__device__ __forceinline__ float fexp2(float x) {
#if __has_builtin(__builtin_amdgcn_exp2f)
    return __builtin_amdgcn_exp2f(x);
#else
    return __expf(x * 0.69314718f);
#endif
}
__device__ __forceinline__ unsigned cvtpk_bf16(float lo_, float hi_) {
    unsigned r;
    asm("v_cvt_pk_bf16_f32 %0, %1, %2" : "=v"(r) : "v"(lo_), "v"(hi_));
    return r;
}
// HW semantics of v_permlane32_swap_b32 (vdst=a, vsrc=b): a's HIGH half swaps
// with b's LOW half. Result: a_new = {a_lo, b_lo}; b_new = {a_hi, b_hi}.
__device__ __forceinline__ void plswap(unsigned& a, unsigned& b) {
#if __has_builtin(__builtin_amdgcn_permlane32_swap)
    typedef int v2i __attribute__((ext_vector_type(2)));
    v2i r = __builtin_amdgcn_permlane32_swap((int)a, (int)b, false, false);
    a = (unsigned)r.x;
    b = (unsigned)r.y;
#else
    unsigned pa_ = (unsigned)__shfl_xor((int)a, 32);
    unsigned pb_ = (unsigned)__shfl_xor((int)b, 32);
    bool hi = (threadIdx.x & 63) >= 32;
    unsigned na = hi ? pb_ : a;
    unsigned nb = hi ? b : pa_;
    a = na;
    b = nb;
#endif
}

// ---------------- fused prep: weight cvt (blocks 0..5119) + LN1 (blocks 5120..21503) ----------------
__global__ __launch_bounds__(256) void prep_kernel(const float* __restrict__ s0,
                                                   const float* __restrict__ s1,
                                                   const float* __restrict__ s2,
                                                   const float* __restrict__ s3,
                                                   const float* __restrict__ s4,
                                                   unsigned short* __restrict__ wdst,
                                                   const float* __restrict__ x,
                                                   const float* __restrict__ gam,
                                                   const float* __restrict__ bet,
                                                   unsigned short* __restrict__ xnb) {
    int tid = threadIdx.x;
    if (blockIdx.x < 5120) {
        int wsel = blockIdx.x >> 10;
        int i = (blockIdx.x & 1023) * 256 + tid;
        const float* src = s0;
        if (wsel == 1) src = s1;
        else if (wsel == 2) src = s2;
        else if (wsel == 3) src = s3;
        else if (wsel == 4) src = s4;
        float4 v = ((const float4*)src)[i];
        ((ushort4*)wdst)[wsel * 262144 + i] =
            make_ushort4(f2bfu(v.x), f2bfu(v.y), f2bfu(v.z), f2bfu(v.w));
        return;
    }
    int row = blockIdx.x - 5120;
    size_t base = (size_t)row * 1024 + tid * 4;
    float4 v = *(const float4*)(x + base);
    float s = v.x + v.y + v.z + v.w;
    float sq = v.x * v.x + v.y * v.y + v.z * v.z + v.w * v.w;
#pragma unroll
    for (int m = 1; m < 64; m <<= 1) {
        s += __shfl_xor(s, m);
        sq += __shfl_xor(sq, m);
    }
    __shared__ float red[8];
    int w = tid >> 6;
    if ((tid & 63) == 0) { red[w] = s; red[w + 4] = sq; }
    __syncthreads();
    s = red[0] + red[1] + red[2] + red[3];
    sq = red[4] + red[5] + red[6] + red[7];
    float mean = s * (1.0f / 1024.0f);
    float var = fmaxf(sq * (1.0f / 1024.0f) - mean * mean, 0.0f);
    float rstd = rsqrtf(var + 1e-5f);
    float4 g4 = *(const float4*)(gam + tid * 4);
    float4 b4 = *(const float4*)(bet + tid * 4);
    *(ushort4*)(xnb + base) = make_ushort4(
        f2bfu((v.x - mean) * rstd * g4.x + b4.x), f2bfu((v.y - mean) * rstd * g4.y + b4.y),
        f2bfu((v.z - mean) * rstd * g4.z + b4.z), f2bfu((v.w - mean) * rstd * g4.w + b4.w));
}

// ---------------- LN2: bf16 xn + bf16 att -> bf16 out ----------------
__global__ __launch_bounds__(256) void ln2_kernel(const unsigned short* __restrict__ in1,
                                                  const unsigned short* __restrict__ in2,
                                                  const float* __restrict__ gam,
                                                  const float* __restrict__ bet,
                                                  unsigned short* __restrict__ outb) {
    int row = blockIdx.x, tid = threadIdx.x;
    size_t base = (size_t)row * 1024 + tid * 4;
    ushort4 a = *(const ushort4*)(in1 + base);
    ushort4 c = *(const ushort4*)(in2 + base);
    float4 v = make_float4(bfu2f(a.x) + bfu2f(c.x), bfu2f(a.y) + bfu2f(c.y),
                           bfu2f(a.z) + bfu2f(c.z), bfu2f(a.w) + bfu2f(c.w));
    float s = v.x + v.y + v.z + v.w;
    float sq = v.x * v.x + v.y * v.y + v.z * v.z + v.w * v.w;
#pragma unroll
    for (int m = 1; m < 64; m <<= 1) {
        s += __shfl_xor(s, m);
        sq += __shfl_xor(sq, m);
    }
    __shared__ float red[8];
    int w = tid >> 6;
    if ((tid & 63) == 0) { red[w] = s; red[w + 4] = sq; }
    __syncthreads();
    s = red[0] + red[1] + red[2] + red[3];
    sq = red[4] + red[5] + red[6] + red[7];
    float mean = s * (1.0f / 1024.0f);
    float var = fmaxf(sq * (1.0f / 1024.0f) - mean * mean, 0.0f);
    float rstd = rsqrtf(var + 1e-5f);
    float4 g4 = *(const float4*)(gam + tid * 4);
    float4 b4 = *(const float4*)(bet + tid * 4);
    *(ushort4*)(outb + base) = make_ushort4(
        f2bfu((v.x - mean) * rstd * g4.x + b4.x), f2bfu((v.y - mean) * rstd * g4.y + b4.y),
        f2bfu((v.z - mean) * rstd * g4.z + b4.z), f2bfu((v.w - mean) * rstd * g4.w + b4.w));
}

// ---------------- BT-GEMM, 8-phase 256x256 schedule (m201 structure) ----------------
// MODE 0: QKV fused (N=3072): col<1024 -> q*0.125log2e, <2048 -> k, else vT[b,h,d,s]
// MODE 1: bias+relu -> bf16. MODE 2: bias + bf16 resid -> f32.
template <int MODE>
__global__ __launch_bounds__(512, 2) void gemm8(const unsigned short* __restrict__ A,
                                                const unsigned short* __restrict__ Bw,
                                                const float* __restrict__ bias,
                                                const unsigned short* __restrict__ resid,
                                                void* __restrict__ O0, void* __restrict__ O1,
                                                void* __restrict__ O2, int M, int N, int K) {
    __shared__ unsigned short As[4][8192];   // [buf*2+half][128*64]
    __shared__ unsigned short Bs[4][8192];
    int nt = N >> 8;
    int bid = blockIdx.x;
    int nwg = gridDim.x;                     // divisible by 8
    int swz = (bid & 7) * (nwg >> 3) + (bid >> 3);
    int mt = swz / nt, ntl = swz % nt;
    int mbase = mt << 8, nbase = ntl << 8;
    int tid = threadIdx.x;
    int w = tid >> 6, l = tid & 63;
    int wm = w >> 2, wn = w & 3;
    int lr = l & 15, lg = l >> 4;
    int lx = lr & 7;
    int brow = (wn & 1) * 64;

    int srow = tid >> 3;
    int csrc = (tid & 7) ^ (srow & 7);
    const unsigned short* aRow = A + (size_t)(mbase + srow) * K + csrc * 8;
    const unsigned short* bRow = Bw + (size_t)(nbase + srow) * K + csrc * 8;

    const int NT = K >> 6;                   // 16
    auto stA = [&](int buf, int h, int t) {
        if (t >= NT) return;
        const unsigned short* s0 = aRow + (size_t)(h * 128) * K + t * 64;
        GLD16(s0, &As[buf * 2 + h][w * 512]);
        GLD16(s0 + (size_t)64 * K, &As[buf * 2 + h][4096 + w * 512]);
    };
    auto stB = [&](int buf, int h, int t) {
        if (t >= NT) return;
        const unsigned short* s0 = bRow + (size_t)(h * 128) * K + t * 64;
        GLD16(s0, &Bs[buf * 2 + h][w * 512]);
        GLD16(s0 + (size_t)64 * K, &Bs[buf * 2 + h][4096 + w * 512]);
    };

    f32x4 acc[8][4] = {};
    bf16x8 afr[4][2], bq0[2][2], bq1[2][2];

    auto rdA = [&](int buf, int mq) {
        const unsigned short* base = &As[buf * 2 + wm][0];
#pragma unroll
        for (int mf = 0; mf < 4; mf++)
#pragma unroll
            for (int ks = 0; ks < 2; ks++)
                afr[mf][ks] = *(const bf16x8*)(base + (mq * 64 + mf * 16 + lr) * 64 +
                                               (((ks * 4 + lg) ^ lx) << 3));
    };
    auto rdB = [&](int buf, int nq, bf16x8 (&bf)[2][2]) {
        const unsigned short* base = &Bs[buf * 2 + (wn >> 1)][0];
#pragma unroll
        for (int nf = 0; nf < 2; nf++)
#pragma unroll
            for (int ks = 0; ks < 2; ks++)
                bf[nf][ks] = *(const bf16x8*)(base + (brow + nq * 32 + nf * 16 + lr) * 64 +
                                              (((ks * 4 + lg) ^ lx) << 3));
    };
    auto MM = [&](int mq, int nq, bf16x8 (&bf)[2][2]) {
        __builtin_amdgcn_s_setprio(1);
#pragma unroll
        for (int mf = 0; mf < 4; mf++)
#pragma unroll
            for (int nf = 0; nf < 2; nf++)
#pragma unroll
                for (int ks = 0; ks < 2; ks++)
                    acc[mq * 4 + mf][nq * 2 + nf] =
                        MFMA_B16(afr[mf][ks], bf[nf][ks], acc[mq * 4 + mf][nq * 2 + nf]);
        __builtin_amdgcn_s_setprio(0);
    };
#define BARX __builtin_amdgcn_s_barrier()
#define LGK0 do { asm volatile("s_waitcnt lgkmcnt(0)" ::: "memory"); \
                  __builtin_amdgcn_sched_barrier(0); } while (0)
#define VMC(n) asm volatile("s_waitcnt vmcnt(" #n ")" ::: "memory")

    stA(0, 0, 0); stA(0, 1, 0); stB(0, 0, 0); stB(0, 1, 0); stB(1, 0, 1); stB(1, 1, 1);
    VMC(4);
    BARX;

    int NIT = NT >> 1;
    for (int i = 0; i < NIT; i++) {
        int t0 = 2 * i, t1 = t0 + 1;
        bool lastI = (i == NIT - 1);
        rdA(0, 0); rdB(0, 0, bq0); stA(1, 0, t1);
        BARX; LGK0; MM(0, 0, bq0); BARX;
        rdB(0, 1, bq1); stA(1, 1, t1);
        BARX; LGK0; MM(0, 1, bq1); BARX;
        rdA(0, 1); stB(0, 0, t0 + 2);
        BARX; LGK0; MM(1, 1, bq1); BARX;
        stB(0, 1, t0 + 2);
        if (lastI) { VMC(0); } else { VMC(4); }
        BARX; MM(1, 0, bq0); BARX;
        rdA(1, 0); rdB(1, 0, bq0); stA(0, 0, t0 + 2);
        BARX; LGK0; MM(0, 0, bq0); BARX;
        rdB(1, 1, bq1); stA(0, 1, t0 + 2);
        BARX; LGK0; MM(0, 1, bq1); BARX;
        rdA(1, 1); stB(1, 0, t1 + 2);
        BARX; LGK0; MM(1, 1, bq1); BARX;
        stB(1, 1, t1 + 2);
        if (!lastI) { VMC(4); }
        BARX; MM(1, 0, bq0); BARX;
    }

#pragma unroll
    for (int m = 0; m < 8; m++) {
        int row = mbase + wm * 128 + (m >> 2) * 64 + (m & 3) * 16 + lg * 4;
#pragma unroll
        for (int n = 0; n < 4; n++) {
            int col = nbase + wn * 64 + (n >> 1) * 32 + (n & 1) * 16 + lr;
            if constexpr (MODE == 0) {
                int wsel = col >> 10;
                int cl = col & 1023;
                if (wsel == 2) {
                    int hh = cl >> 6, dd = cl & 63;
                    int bb = row >> 11, ss = row & 2047;
                    unsigned short t4[4];
#pragma unroll
                    for (int j = 0; j < 4; j++) t4[j] = f2bfu(acc[m][n][j]);
                    size_t vtidx = ((size_t)((bb * 16 + hh) * 64 + dd)) * 2048 + ss;
                    *(uint2*)((unsigned short*)O2 + vtidx) = *(uint2*)t4;
                } else {
                    unsigned short* out = (wsel == 0) ? (unsigned short*)O0 : (unsigned short*)O1;
                    float sc = (wsel == 0) ? 0.18033688f : 1.0f;   // 0.125*log2e folded into Q
#pragma unroll
                    for (int j = 0; j < 4; j++)
                        out[(size_t)(row + j) * 1024 + cl] = f2bfu(acc[m][n][j] * sc);
                }
            } else {
                float bv = bias[col];
#pragma unroll
                for (int j = 0; j < 4; j++) {
                    float v = acc[m][n][j] + bv;
                    size_t idx = (size_t)(row + j) * N + col;
                    if constexpr (MODE == 1) {
                        ((unsigned short*)O0)[idx] = f2bfu(fmaxf(v, 0.0f));
                    } else {
                        ((float*)O0)[idx] = v + bfu2f(resid[idx]);
                    }
                }
            }
        }
    }
#undef BARX
#undef LGK0
#undef VMC
}

// ---------------- flash attention: 4-buffer depth-2 counted-vmcnt (R9 best) ----------------
// 8 waves x QBLK=32, KVBLK=64, zero-shift softmax, swapped-QK 32x32 MFMA.
// Per step: stage(s+2) -> vmcnt(4) [tile s landed; s+1,s+2 in flight] -> s_barrier
// -> compute tile s. Overwrite of buf[(s+2)&3] is 1 full barrier after its reads.
__global__ __launch_bounds__(512) void attn_kernel(const unsigned short* __restrict__ qq,
                                                   const unsigned short* __restrict__ kk,
                                                   const unsigned short* __restrict__ vT,
                                                   unsigned short* __restrict__ attb) {
    __shared__ unsigned short Ks[4][64 * 64];   // [buf][key][d], chunk-XOR swizzled
    __shared__ unsigned short Vs[4][64 * 64];   // [buf][d][key]

    int bid = blockIdx.x;
    int swz = (bid & 7) * (gridDim.x >> 3) + (bid >> 3);   // gridDim=1024, %8==0
    int qi = swz & 7, h = (swz >> 3) & 15, b = swz >> 7;
    int tid = threadIdx.x, w = tid >> 6, l = tid & 63;
    int lo = l & 31, hi = l >> 5;
    int q0 = qi * 256 + w * 32;

    const unsigned short* qp = qq + ((size_t)((b * 2048 + q0 + lo) * 16 + h)) * 64 + hi * 8;
    bf16x8 qf[4];
#pragma unroll
    for (int kc = 0; kc < 4; kc++) qf[kc] = *(const bf16x8*)(qp + kc * 16);

    int srow = w * 8 + (l >> 3);
    int schunk = (l & 7) ^ ((l >> 3) & 7);
    const unsigned short* ksrc0 = kk + ((size_t)((b * 2048 + srow) * 16 + h)) * 64 + schunk * 8;
    const unsigned short* vsrc0 = vT + ((size_t)((b * 16 + h) * 64 + srow)) * 2048 + schunk * 8;

    auto stageT = [&](int s) {                   // stage tile s into buf s&3
        if (s > 31) return;
        GLD16(ksrc0 + (size_t)s * 65536, &Ks[s & 3][w * 512]);
        GLD16(vsrc0 + (size_t)s * 64, &Vs[s & 3][w * 512]);
    };

    f32x16 od0 = {}, od1 = {};
    float ssum = 0.f;

    stageT(0); stageT(1);

    for (int s = 0; s < 32; s++) {
        stageT(s + 2);
        if (s < 30) asm volatile("s_waitcnt vmcnt(4)" ::: "memory");
        else if (s == 30) asm volatile("s_waitcnt vmcnt(2)" ::: "memory");
        else asm volatile("s_waitcnt vmcnt(0)" ::: "memory");
        __builtin_amdgcn_s_barrier();            // tile s complete for ALL waves
        __builtin_amdgcn_sched_barrier(0);       // keep reads below the barrier

        const unsigned short* Kb = &Ks[s & 3][0];
        const unsigned short* Vb = &Vs[s & 3][0];

        // ---- QK^T (swapped): St[key][q] ----
        f32x16 sacc[2];
        __builtin_amdgcn_s_setprio(1);
#pragma unroll
        for (int tt = 0; tt < 2; tt++) {
            f32x16 sv = {};
            int row = tt * 32 + lo;
#pragma unroll
            for (int kc = 0; kc < 4; kc++) {
                bf16x8 a = *(const bf16x8*)(Kb + row * 64 + (((kc * 2 + hi) ^ (row & 7)) << 3));
                sv = MFMA32_B16(a, qf[kc], sv);
            }
            sacc[tt] = sv;
        }
        __builtin_amdgcn_s_setprio(0);
        // ---- zero-shift softmax, two interleaved psum chains ----
        float p[32];
        float ps0 = 0.f, ps1 = 0.f;
#pragma unroll
        for (int r = 0; r < 16; r++) {
            float e0 = fexp2(sacc[0][r]);
            float e1 = fexp2(sacc[1][r]);
            p[r] = e0;
            p[16 + r] = e1;
            ps0 += e0;
            ps1 += e1;
        }
        float psum = ps0 + ps1;
        psum += __shfl_xor(psum, 32);
        ssum += psum;
        // ---- P -> bf16 A-frags in-register + PV ----
#pragma unroll
        for (int tt = 0; tt < 2; tt++) {
            unsigned wv[8];
#pragma unroll
            for (int i = 0; i < 8; i++) wv[i] = cvtpk_bf16(p[tt * 16 + 2 * i], p[tt * 16 + 2 * i + 1]);
            plswap(wv[0], wv[2]);
            plswap(wv[1], wv[3]);
            plswap(wv[4], wv[6]);
            plswap(wv[5], wv[7]);
            union { unsigned u[4]; bf16x8 v; } c0, c1;
            c0.u[0] = wv[0]; c0.u[1] = wv[1]; c0.u[2] = wv[2]; c0.u[3] = wv[3];
            c1.u[0] = wv[4]; c1.u[1] = wv[5]; c1.u[2] = wv[6]; c1.u[3] = wv[7];
            __builtin_amdgcn_s_setprio(1);
#pragma unroll
            for (int sub = 0; sub < 2; sub++) {
                int ks = tt * 2 + sub;
                bf16x8 pa = sub ? c1.v : c0.v;
                int slot = ((ks * 2 + hi) ^ (lo & 7)) << 3;
                bf16x8 v0 = *(const bf16x8*)(Vb + lo * 64 + slot);
                bf16x8 v1 = *(const bf16x8*)(Vb + (32 + lo) * 64 + slot);
                od0 = MFMA32_B16(pa, v0, od0);
                od1 = MFMA32_B16(pa, v1, od1);
            }
            __builtin_amdgcn_s_setprio(0);
        }
    }

#pragma unroll
    for (int r = 0; r < 16; r++) {
        int crow = (r & 3) + ((r >> 2) << 3) + (hi << 2);
        float rs = 1.0f / __shfl(ssum, crow);
        int q = q0 + crow;
        size_t base = ((size_t)((b * 2048 + q) * 16 + h)) * 64;
        attb[base + lo] = f2bfu(od0[r] * rs);
        attb[base + 32 + lo] = f2bfu(od1[r] * rs);
    }
}

// ---------------- launch ----------------
extern "C" void kernel_launch(void* const* d_in, const int* in_sizes, int n_in,
                              void* d_out, int out_size, void* d_ws, size_t ws_size,
                              hipStream_t stream) {
    const float* x = (const float*)d_in[0];
    const float* wq = (const float*)d_in[1];
    const float* wk = (const float*)d_in[2];
    const float* wv = (const float*)d_in[3];
    const float* ln1_g = (const float*)d_in[4];
    const float* ln1_b = (const float*)d_in[5];
    const float* ln2_g = (const float*)d_in[6];
    const float* ln2_b = (const float*)d_in[7];
    const float* w1 = (const float*)d_in[8];
    const float* b1 = (const float*)d_in[9];
    const float* w2 = (const float*)d_in[10];
    const float* b2 = (const float*)d_in[11];

    const size_t NB = 33554432;                 // bytes per bf16 [B,S,D] buffer
    char* ws = (char*)d_ws;
    unsigned short* xn_b = (unsigned short*)(ws);
    unsigned short* q_b = (unsigned short*)(ws + NB);
    unsigned short* k_b = (unsigned short*)(ws + 2 * NB);
    unsigned short* vT_b = (unsigned short*)(ws + 3 * NB);
    unsigned short* att_b = (unsigned short*)(ws + 4 * NB);
    unsigned short* wq_b = (unsigned short*)(ws + 5 * NB);   // wq,wk,wv,w1,w2 contiguous
    unsigned short* w1_b = wq_b + 3145728;
    unsigned short* w2_b = w1_b + 1048576;
    // stream-ordered reuse:
    unsigned short* xt_b = q_b;                 // q dead after attention
    unsigned short* h_b = k_b;                  // k dead after attention

    dim3 blk(256);
    prep_kernel<<<21504, blk, 0, stream>>>(wq, wk, wv, w1, w2, wq_b,
                                           x, ln1_g, ln1_b, xn_b);

    gemm8<0><<<768, dim3(512), 0, stream>>>(xn_b, wq_b, nullptr, nullptr,
                                            q_b, k_b, vT_b, 16384, 3072, 1024);

    attn_kernel<<<1024, dim3(512), 0, stream>>>(q_b, k_b, vT_b, att_b);

    ln2_kernel<<<16384, blk, 0, stream>>>(xn_b, att_b, ln2_g, ln2_b, xt_b);

    gemm8<1><<<256, dim3(512), 0, stream>>>(xt_b, w1_b, b1, nullptr,
                                            h_b, nullptr, nullptr, 16384, 1024, 1024);
    gemm8<2><<<256, dim3(512), 0, stream>>>(h_b, w2_b, b2, xt_b,
                                            d_out, nullptr, nullptr, 16384, 1024, 1024);
}